// Round 1
// baseline (918.550 us; speedup 1.0000x reference)
//
#include <hip/hip_runtime.h>
#include <math.h>
#include <stdint.h>

// ---------------------------------------------------------------------------
// GCNNet forward, MI355X. Structure:
//   deg/hist -> scan -> CSR scatter (per-launch preprocessing, int atomics only)
//   stats(x) -> fold BN into W -> matmul -> h1
//   3x [ stats(h) -> fold -> matmul -> xw -> CSR propagate(+bias,relu) -> h ]
//   pool (sorted batch, binary-searched segment starts, no atomics)
//   stats(hg) -> fold(fc) -> matmul(128x128) -> stats -> final BN+cls+logsoftmax
// ---------------------------------------------------------------------------

#define EPS 1e-5f

__global__ __launch_bounds__(256) void k_deg_hist(const int* __restrict__ src,
                                                  const int* __restrict__ dst,
                                                  int e, int* __restrict__ deg,
                                                  int* __restrict__ cnt) {
  int i = blockIdx.x * 256 + threadIdx.x;
  if (i < e) {
    atomicAdd(&deg[src[i]], 1);
    atomicAdd(&cnt[dst[i]], 1);
  }
}

__global__ __launch_bounds__(256) void k_dis(const int* __restrict__ deg,
                                             float* __restrict__ dis, int n) {
  int i = blockIdx.x * 256 + threadIdx.x;
  if (i < n) dis[i] = rsqrtf((float)(deg[i] + 1));  // +1 self loop
}

__global__ __launch_bounds__(1024) void k_scan(const int* __restrict__ cnt,
                                               int* __restrict__ row_ptr, int n) {
  __shared__ int tmp[1024];
  __shared__ int carry;
  int t = threadIdx.x;
  if (t == 0) { carry = 0; row_ptr[0] = 0; }
  __syncthreads();
  for (int base = 0; base < n; base += 1024) {
    int i = base + t;
    int v = (i < n) ? cnt[i] : 0;
    tmp[t] = v;
    __syncthreads();
    for (int off = 1; off < 1024; off <<= 1) {
      int add = (t >= off) ? tmp[t - off] : 0;
      __syncthreads();
      tmp[t] += add;
      __syncthreads();
    }
    int inc = tmp[t] + carry;
    if (i < n) row_ptr[i + 1] = inc;
    __syncthreads();
    if (t == 1023) carry = inc;
    __syncthreads();
  }
}

__global__ __launch_bounds__(256) void k_scatter(const int* __restrict__ src,
                                                 const int* __restrict__ dst, int e,
                                                 const float* __restrict__ dis,
                                                 int* __restrict__ cursor,
                                                 int* __restrict__ esrc,
                                                 float* __restrict__ enorm) {
  int i = blockIdx.x * 256 + threadIdx.x;
  if (i < e) {
    int s = src[i], d = dst[i];
    int p = atomicAdd(&cursor[d], 1);
    esrc[p] = s;
    enorm[p] = dis[s] * dis[d];
  }
}

// column sums / sumsq over n rows of a (n,128) row-major matrix
__global__ __launch_bounds__(256) void k_stats(const float* __restrict__ h, int n,
                                               float* __restrict__ sums) {
  int c = threadIdx.x & 127;
  int half = threadIdx.x >> 7;
  float s = 0.f, s2 = 0.f;
  for (int r = blockIdx.x * 2 + half; r < n; r += gridDim.x * 2) {
    float v = h[(size_t)r * 128 + c];
    s += v;
    s2 += v * v;
  }
  __shared__ float ls[256];
  __shared__ float ls2[256];
  ls[threadIdx.x] = s;
  ls2[threadIdx.x] = s2;
  __syncthreads();
  if (half == 0) {
    atomicAdd(&sums[c], ls[c] + ls[c + 128]);
    atomicAdd(&sums[128 + c], ls2[c] + ls2[c + 128]);
  }
}

// fold BN (gamma g, beta b, batch stats in sums) into W: Wf = A[k]*W[k][j],
// biasf[j] = sum_k B[k]*W[k][j] (+ extra[j])
__global__ __launch_bounds__(128) void k_fold(const float* __restrict__ g,
                                              const float* __restrict__ b,
                                              const float* __restrict__ W,
                                              const float* __restrict__ sums,
                                              float inv_n,
                                              const float* __restrict__ extra,
                                              float* __restrict__ Wf,
                                              float* __restrict__ biasf) {
  __shared__ float A[128], B[128];
  int t = threadIdx.x;
  float m = sums[t] * inv_n;
  float v = sums[128 + t] * inv_n - m * m;
  float rs = rsqrtf(v + EPS);
  float a = g[t] * rs;
  A[t] = a;
  B[t] = b[t] - a * m;
  __syncthreads();
  float bias = extra ? extra[t] : 0.f;
  for (int k = 0; k < 128; ++k) {
    float w = W[k * 128 + t];
    Wf[k * 128 + t] = A[k] * w;
    bias += B[k] * w;
  }
  biasf[t] = bias;
}

// out[n,128] = (optional relu)( in[n,128] @ W[128,128] + bias ), fp32 vector,
// 64-row tile per block, per-thread 4 rows x 8 cols register tile.
__global__ __launch_bounds__(256) void k_matmul(const float* __restrict__ in,
                                                const float* __restrict__ W,
                                                const float* __restrict__ bias,
                                                float* __restrict__ out, int n,
                                                int relu) {
  __shared__ float sW[128 * 128];   // 64 KB
  __shared__ float sH[64 * 129];    // 33 KB, padded stride 129
  int tid = threadIdx.x;
  int row0 = blockIdx.x * 64;
  const float4* W4 = (const float4*)W;
  float4* sW4 = (float4*)sW;
#pragma unroll
  for (int i = 0; i < 16; ++i) sW4[tid + i * 256] = W4[tid + i * 256];
  for (int i = tid; i < 64 * 32; i += 256) {
    int r = i >> 5, c4 = i & 31;
    int gr = row0 + r;
    float4 v = make_float4(0.f, 0.f, 0.f, 0.f);
    if (gr < n) v = ((const float4*)(in + (size_t)gr * 128))[c4];
    float* dp = &sH[r * 129 + (c4 << 2)];
    dp[0] = v.x; dp[1] = v.y; dp[2] = v.z; dp[3] = v.w;
  }
  __syncthreads();
  int tx = tid & 15, ty = tid >> 4;
  int col0 = tx * 8;
  float acc[4][8];
#pragma unroll
  for (int i = 0; i < 4; ++i)
#pragma unroll
    for (int j = 0; j < 8; ++j) acc[i][j] = bias[col0 + j];
  for (int k = 0; k < 128; ++k) {
    float hv[4];
#pragma unroll
    for (int i = 0; i < 4; ++i) hv[i] = sH[(ty * 4 + i) * 129 + k];
    const float* wr = &sW[k * 128 + col0];
    float4 wa = *(const float4*)wr;
    float4 wb = *(const float4*)(wr + 4);
    float wv[8] = {wa.x, wa.y, wa.z, wa.w, wb.x, wb.y, wb.z, wb.w};
#pragma unroll
    for (int i = 0; i < 4; ++i)
#pragma unroll
      for (int j = 0; j < 8; ++j) acc[i][j] += hv[i] * wv[j];
  }
#pragma unroll
  for (int i = 0; i < 4; ++i) {
    int gr = row0 + ty * 4 + i;
    if (gr < n) {
      float o[8];
#pragma unroll
      for (int j = 0; j < 8; ++j)
        o[j] = relu ? fmaxf(acc[i][j], 0.f) : acc[i][j];
      float4* dp = (float4*)(out + (size_t)gr * 128 + col0);
      dp[0] = make_float4(o[0], o[1], o[2], o[3]);
      dp[1] = make_float4(o[4], o[5], o[6], o[7]);
    }
  }
}

// CSR propagate: out[d] = relu( sum_e norm*xw[src] + dis[d]^2*xw[d] + bconv )
// one wave per node, lane covers cols {lane, lane+64}
__global__ __launch_bounds__(256) void k_prop(const float* __restrict__ xw,
                                              const int* __restrict__ row_ptr,
                                              const int* __restrict__ esrc,
                                              const float* __restrict__ enorm,
                                              const float* __restrict__ dis,
                                              const float* __restrict__ bconv,
                                              float* __restrict__ out, int n) {
  int wave = threadIdx.x >> 6;
  int lane = threadIdx.x & 63;
  int node = blockIdx.x * 4 + wave;
  if (node >= n) return;
  int s = row_ptr[node], e = row_ptr[node + 1];
  float a0 = 0.f, a1 = 0.f;
  int p = s;
  for (; p + 1 < e; p += 2) {
    int s0 = esrc[p], s1 = esrc[p + 1];
    float n0 = enorm[p], n1 = enorm[p + 1];
    const float* x0 = xw + (size_t)s0 * 128;
    const float* x1 = xw + (size_t)s1 * 128;
    a0 += n0 * x0[lane];
    a1 += n0 * x0[lane + 64];
    a0 += n1 * x1[lane];
    a1 += n1 * x1[lane + 64];
  }
  if (p < e) {
    int s0 = esrc[p];
    float n0 = enorm[p];
    const float* x0 = xw + (size_t)s0 * 128;
    a0 += n0 * x0[lane];
    a1 += n0 * x0[lane + 64];
  }
  float d = dis[node];
  const float* xs = xw + (size_t)node * 128;
  a0 += d * d * xs[lane];
  a1 += d * d * xs[lane + 64];
  a0 = fmaxf(a0 + bconv[lane], 0.f);
  a1 = fmaxf(a1 + bconv[lane + 64], 0.f);
  out[(size_t)node * 128 + lane] = a0;
  out[(size_t)node * 128 + 64 + lane] = a1;
}

__global__ __launch_bounds__(256) void k_gstart(const int* __restrict__ batch, int n,
                                                int* __restrict__ gstart) {
  int g = threadIdx.x;
  if (g > 128) return;
  int lo = 0, hi = n;
  while (lo < hi) {
    int mid = (lo + hi) >> 1;
    if (batch[mid] < g) lo = mid + 1; else hi = mid;
  }
  gstart[g] = lo;
}

__global__ __launch_bounds__(128) void k_pool(const float* __restrict__ h,
                                              const int* __restrict__ gstart,
                                              float* __restrict__ hg) {
  int g = blockIdx.x;
  int c = threadIdx.x;
  int s = gstart[g], e = gstart[g + 1];
  float acc = 0.f;
  for (int r = s; r < e; ++r) acc += h[(size_t)r * 128 + c];
  hg[g * 128 + c] = acc;
}

// final: BN(bn_hid) on hg2, @ w_cls + b_cls, row log_softmax. 1 wave / graph.
__global__ __launch_bounds__(64) void k_final(const float* __restrict__ hg2,
                                              const float* __restrict__ sums,
                                              const float* __restrict__ g,
                                              const float* __restrict__ b,
                                              const float* __restrict__ w_cls,
                                              const float* __restrict__ b_cls,
                                              float* __restrict__ out) {
  int gid = blockIdx.x;
  int l = threadIdx.x;
  float m0 = sums[l] * (1.f / 128.f);
  float v0 = sums[128 + l] * (1.f / 128.f) - m0 * m0;
  float A0 = g[l] * rsqrtf(v0 + EPS);
  float B0 = b[l] - A0 * m0;
  float m1 = sums[l + 64] * (1.f / 128.f);
  float v1 = sums[128 + l + 64] * (1.f / 128.f) - m1 * m1;
  float A1 = g[l + 64] * rsqrtf(v1 + EPS);
  float B1 = b[l + 64] - A1 * m1;
  float a0 = A0 * hg2[gid * 128 + l] + B0;
  float a1 = A1 * hg2[gid * 128 + 64 + l] + B1;
  float logit[10];
#pragma unroll
  for (int c = 0; c < 10; ++c) {
    float p = a0 * w_cls[l * 10 + c] + a1 * w_cls[(l + 64) * 10 + c];
#pragma unroll
    for (int off = 32; off; off >>= 1) p += __shfl_xor(p, off, 64);
    logit[c] = p + b_cls[c];
  }
  if (l == 0) {
    float mx = logit[0];
#pragma unroll
    for (int c = 1; c < 10; ++c) mx = fmaxf(mx, logit[c]);
    float se = 0.f;
#pragma unroll
    for (int c = 0; c < 10; ++c) se += expf(logit[c] - mx);
    float lse = mx + logf(se);
#pragma unroll
    for (int c = 0; c < 10; ++c) out[gid * 10 + c] = logit[c] - lse;
  }
}

static inline char* alignp(char* p, size_t a) {
  return (char*)(((uintptr_t)p + a - 1) & ~(a - 1));
}

extern "C" void kernel_launch(void* const* d_in, const int* in_sizes, int n_in,
                              void* d_out, int out_size, void* d_ws, size_t ws_size,
                              hipStream_t stream) {
  const float* x         = (const float*)d_in[0];
  const int*   ei        = (const int*)d_in[1];
  const int*   batch     = (const int*)d_in[2];
  const float* bn_feat_g = (const float*)d_in[3];
  const float* bn_feat_b = (const float*)d_in[4];
  const float* w_feat    = (const float*)d_in[5];
  const float* bn_conv_g = (const float*)d_in[6];
  const float* bn_conv_b = (const float*)d_in[7];
  const float* w_conv    = (const float*)d_in[8];
  const float* b_conv    = (const float*)d_in[9];
  const float* bn_fc_g   = (const float*)d_in[10];
  const float* bn_fc_b   = (const float*)d_in[11];
  const float* w_fc      = (const float*)d_in[12];
  const float* b_fc      = (const float*)d_in[13];
  const float* bn_hid_g  = (const float*)d_in[14];
  const float* bn_hid_b  = (const float*)d_in[15];
  const float* w_cls     = (const float*)d_in[16];
  const float* b_cls     = (const float*)d_in[17];
  float* out = (float*)d_out;

  const int N = in_sizes[0] / 128;
  const int E = in_sizes[1] / 2;
  const int* src = ei;
  const int* dst = ei + E;

  char* p = (char*)d_ws;
  auto carve = [&](size_t bytes) {
    char* q = alignp(p, 256);
    p = q + bytes;
    return q;
  };
  float* dis    = (float*)carve((size_t)N * 4);
  int*   deg    = (int*)carve((size_t)2 * N * 4);  // deg | cnt adjacent
  int*   cnt    = deg + N;
  int*   rowp   = (int*)carve((size_t)(N + 1) * 4);
  int*   cursor = (int*)carve((size_t)N * 4);
  int*   esrc   = (int*)carve((size_t)E * 4);
  float* enorm  = (float*)carve((size_t)E * 4);
  float* sums   = (float*)carve(256 * 4);
  float* Wf     = (float*)carve(16384 * 4);
  float* biasf  = (float*)carve(128 * 4);
  float* h      = (float*)carve((size_t)N * 128 * 4);
  float* xw     = (float*)carve((size_t)N * 128 * 4);
  float* hg     = (float*)carve(16384 * 4);
  float* hg2    = (float*)carve(16384 * 4);
  int*   gstart = (int*)carve(129 * 4);

  const int EB = (E + 255) / 256;
  const int NB = (N + 255) / 256;
  const int MMB = (N + 63) / 64;
  const int PB = (N + 3) / 4;

  // --- graph preprocessing (same every launch) ---
  hipMemsetAsync(deg, 0, (size_t)2 * N * 4, stream);
  k_deg_hist<<<EB, 256, 0, stream>>>(src, dst, E, deg, cnt);
  k_dis<<<NB, 256, 0, stream>>>(deg, dis, N);
  k_scan<<<1, 1024, 0, stream>>>(cnt, rowp, N);
  hipMemcpyAsync(cursor, rowp, (size_t)N * 4, hipMemcpyDeviceToDevice, stream);
  k_scatter<<<EB, 256, 0, stream>>>(src, dst, E, dis, cursor, esrc, enorm);
  k_gstart<<<1, 256, 0, stream>>>(batch, N, gstart);

  // --- feat layer: h = relu(BN(x) @ w_feat) ---
  hipMemsetAsync(sums, 0, 256 * 4, stream);
  k_stats<<<256, 256, 0, stream>>>(x, N, sums);
  k_fold<<<1, 128, 0, stream>>>(bn_feat_g, bn_feat_b, w_feat, sums, 1.f / N,
                                nullptr, Wf, biasf);
  k_matmul<<<MMB, 256, 0, stream>>>(x, Wf, biasf, h, N, 1);

  // --- 3 conv layers ---
  for (int i = 0; i < 3; ++i) {
    hipMemsetAsync(sums, 0, 256 * 4, stream);
    k_stats<<<256, 256, 0, stream>>>(h, N, sums);
    k_fold<<<1, 128, 0, stream>>>(bn_conv_g + i * 128, bn_conv_b + i * 128,
                                  w_conv + (size_t)i * 16384, sums, 1.f / N,
                                  nullptr, Wf, biasf);
    k_matmul<<<MMB, 256, 0, stream>>>(h, Wf, biasf, xw, N, 0);
    k_prop<<<PB, 256, 0, stream>>>(xw, rowp, esrc, enorm, dis, b_conv + i * 128,
                                   h, N);
  }

  // --- pool + head ---
  k_pool<<<128, 128, 0, stream>>>(h, gstart, hg);

  hipMemsetAsync(sums, 0, 256 * 4, stream);
  k_stats<<<16, 256, 0, stream>>>(hg, 128, sums);
  k_fold<<<1, 128, 0, stream>>>(bn_fc_g, bn_fc_b, w_fc, sums, 1.f / 128.f, b_fc,
                                Wf, biasf);
  k_matmul<<<2, 256, 0, stream>>>(hg, Wf, biasf, hg2, 128, 1);

  hipMemsetAsync(sums, 0, 256 * 4, stream);
  k_stats<<<16, 256, 0, stream>>>(hg2, 128, sums);
  k_final<<<128, 64, 0, stream>>>(hg2, sums, bn_hid_g, bn_hid_b, w_cls, b_cls,
                                  out);
}

// Round 2
// 759.491 us; speedup vs baseline: 1.2094x; 1.2094x over previous
//
#include <hip/hip_runtime.h>
#include <math.h>
#include <stdint.h>

// ---------------------------------------------------------------------------
// GCNNet forward, MI355X.
// R2: node-parallel pool (was 105us serial-per-graph walk, 2.4% occupancy),
//     3-phase parallel scan (was single-block serial scan over 50k).
// ---------------------------------------------------------------------------

#define EPS 1e-5f

__global__ __launch_bounds__(256) void k_deg_hist(const int* __restrict__ src,
                                                  const int* __restrict__ dst,
                                                  int e, int* __restrict__ deg,
                                                  int* __restrict__ cnt) {
  int i = blockIdx.x * 256 + threadIdx.x;
  if (i < e) {
    atomicAdd(&deg[src[i]], 1);
    atomicAdd(&cnt[dst[i]], 1);
  }
}

__global__ __launch_bounds__(256) void k_dis(const int* __restrict__ deg,
                                             float* __restrict__ dis, int n) {
  int i = blockIdx.x * 256 + threadIdx.x;
  if (i < n) dis[i] = rsqrtf((float)(deg[i] + 1));  // +1 self loop
}

// --- 3-phase scan: block-local inclusive scan -> scan block sums -> add ---
__global__ __launch_bounds__(256) void k_scan1(const int* __restrict__ cnt, int n,
                                               int* __restrict__ rowp,
                                               int* __restrict__ bsum) {
  __shared__ int ls[256];
  int base = blockIdx.x * 1024;
  int t = threadIdx.x;
  int idx = base + t * 4;
  int v[4];
#pragma unroll
  for (int j = 0; j < 4; ++j) v[j] = (idx + j < n) ? cnt[idx + j] : 0;
  int tot = v[0] + v[1] + v[2] + v[3];
  v[1] += v[0]; v[2] += v[1]; v[3] += v[2];
  ls[t] = tot;
  __syncthreads();
  for (int off = 1; off < 256; off <<= 1) {
    int add = (t >= off) ? ls[t - off] : 0;
    __syncthreads();
    ls[t] += add;
    __syncthreads();
  }
  int prefix = (t > 0) ? ls[t - 1] : 0;
#pragma unroll
  for (int j = 0; j < 4; ++j)
    if (idx + j < n) rowp[idx + j + 1] = v[j] + prefix;
  if (t == 255) bsum[blockIdx.x] = ls[255];
}

__global__ __launch_bounds__(64) void k_scan2(int* __restrict__ bsum, int nb) {
  int t = threadIdx.x;
  int orig = (t < nb) ? bsum[t] : 0;
  int v = orig;
  for (int off = 1; off < 64; off <<= 1) {
    int u = __shfl_up(v, off, 64);
    if (t >= off) v += u;
  }
  if (t < nb) bsum[t] = v - orig;  // exclusive
}

// add block offsets; also produce cursor[] = final rowp[] (replaces d2d copy)
__global__ __launch_bounds__(256) void k_scan3(int* __restrict__ rowp,
                                               int* __restrict__ cursor,
                                               const int* __restrict__ bsum, int n) {
  int base = blockIdx.x * 1024;
  int off = bsum[blockIdx.x];
  int t = threadIdx.x;
#pragma unroll
  for (int j = 0; j < 4; ++j) {
    int i = base + t + j * 256;
    if (i < n) {
      int val = rowp[i + 1] + off;
      rowp[i + 1] = val;
      if (i + 1 < n) cursor[i + 1] = val;
    }
  }
  if (blockIdx.x == 0 && t == 0) { rowp[0] = 0; cursor[0] = 0; }
}

__global__ __launch_bounds__(256) void k_scatter(const int* __restrict__ src,
                                                 const int* __restrict__ dst, int e,
                                                 const float* __restrict__ dis,
                                                 int* __restrict__ cursor,
                                                 int* __restrict__ esrc,
                                                 float* __restrict__ enorm) {
  int i = blockIdx.x * 256 + threadIdx.x;
  if (i < e) {
    int s = src[i], d = dst[i];
    int p = atomicAdd(&cursor[d], 1);
    esrc[p] = s;
    enorm[p] = dis[s] * dis[d];
  }
}

// column sums / sumsq over n rows of a (n,128) row-major matrix
__global__ __launch_bounds__(256) void k_stats(const float* __restrict__ h, int n,
                                               float* __restrict__ sums) {
  int c = threadIdx.x & 127;
  int half = threadIdx.x >> 7;
  float s = 0.f, s2 = 0.f;
  for (int r = blockIdx.x * 2 + half; r < n; r += gridDim.x * 2) {
    float v = h[(size_t)r * 128 + c];
    s += v;
    s2 += v * v;
  }
  __shared__ float ls[256];
  __shared__ float ls2[256];
  ls[threadIdx.x] = s;
  ls2[threadIdx.x] = s2;
  __syncthreads();
  if (half == 0) {
    atomicAdd(&sums[c], ls[c] + ls[c + 128]);
    atomicAdd(&sums[128 + c], ls2[c] + ls2[c + 128]);
  }
}

// fold BN into W: Wf[k][j] = A[k]*W[k][j], biasf[j] = sum_k B[k]*W[k][j]+extra
__global__ __launch_bounds__(128) void k_fold(const float* __restrict__ g,
                                              const float* __restrict__ b,
                                              const float* __restrict__ W,
                                              const float* __restrict__ sums,
                                              float inv_n,
                                              const float* __restrict__ extra,
                                              float* __restrict__ Wf,
                                              float* __restrict__ biasf) {
  __shared__ float A[128], B[128];
  int t = threadIdx.x;
  float m = sums[t] * inv_n;
  float v = sums[128 + t] * inv_n - m * m;
  float rs = rsqrtf(v + EPS);
  float a = g[t] * rs;
  A[t] = a;
  B[t] = b[t] - a * m;
  __syncthreads();
  float bias = extra ? extra[t] : 0.f;
  for (int k = 0; k < 128; ++k) {
    float w = W[k * 128 + t];
    Wf[k * 128 + t] = A[k] * w;
    bias += B[k] * w;
  }
  biasf[t] = bias;
}

// out[n,128] = (optional relu)( in[n,128] @ W[128,128] + bias )
__global__ __launch_bounds__(256) void k_matmul(const float* __restrict__ in,
                                                const float* __restrict__ W,
                                                const float* __restrict__ bias,
                                                float* __restrict__ out, int n,
                                                int relu) {
  __shared__ float sW[128 * 128];   // 64 KB
  __shared__ float sH[64 * 129];    // 33 KB
  int tid = threadIdx.x;
  int row0 = blockIdx.x * 64;
  const float4* W4 = (const float4*)W;
  float4* sW4 = (float4*)sW;
#pragma unroll
  for (int i = 0; i < 16; ++i) sW4[tid + i * 256] = W4[tid + i * 256];
  for (int i = tid; i < 64 * 32; i += 256) {
    int r = i >> 5, c4 = i & 31;
    int gr = row0 + r;
    float4 v = make_float4(0.f, 0.f, 0.f, 0.f);
    if (gr < n) v = ((const float4*)(in + (size_t)gr * 128))[c4];
    float* dp = &sH[r * 129 + (c4 << 2)];
    dp[0] = v.x; dp[1] = v.y; dp[2] = v.z; dp[3] = v.w;
  }
  __syncthreads();
  int tx = tid & 15, ty = tid >> 4;
  int col0 = tx * 8;
  float acc[4][8];
#pragma unroll
  for (int i = 0; i < 4; ++i)
#pragma unroll
    for (int j = 0; j < 8; ++j) acc[i][j] = bias[col0 + j];
  for (int k = 0; k < 128; ++k) {
    float hv[4];
#pragma unroll
    for (int i = 0; i < 4; ++i) hv[i] = sH[(ty * 4 + i) * 129 + k];
    const float* wr = &sW[k * 128 + col0];
    float4 wa = *(const float4*)wr;
    float4 wb = *(const float4*)(wr + 4);
    float wv[8] = {wa.x, wa.y, wa.z, wa.w, wb.x, wb.y, wb.z, wb.w};
#pragma unroll
    for (int i = 0; i < 4; ++i)
#pragma unroll
      for (int j = 0; j < 8; ++j) acc[i][j] += hv[i] * wv[j];
  }
#pragma unroll
  for (int i = 0; i < 4; ++i) {
    int gr = row0 + ty * 4 + i;
    if (gr < n) {
      float o[8];
#pragma unroll
      for (int j = 0; j < 8; ++j)
        o[j] = relu ? fmaxf(acc[i][j], 0.f) : acc[i][j];
      float4* dp = (float4*)(out + (size_t)gr * 128 + col0);
      dp[0] = make_float4(o[0], o[1], o[2], o[3]);
      dp[1] = make_float4(o[4], o[5], o[6], o[7]);
    }
  }
}

// CSR propagate: out[d] = relu( sum_e norm*xw[src] + dis[d]^2*xw[d] + bconv )
__global__ __launch_bounds__(256) void k_prop(const float* __restrict__ xw,
                                              const int* __restrict__ row_ptr,
                                              const int* __restrict__ esrc,
                                              const float* __restrict__ enorm,
                                              const float* __restrict__ dis,
                                              const float* __restrict__ bconv,
                                              float* __restrict__ out, int n) {
  int wave = threadIdx.x >> 6;
  int lane = threadIdx.x & 63;
  int node = blockIdx.x * 4 + wave;
  if (node >= n) return;
  int s = row_ptr[node], e = row_ptr[node + 1];
  float a0 = 0.f, a1 = 0.f;
  int p = s;
  for (; p + 1 < e; p += 2) {
    int s0 = esrc[p], s1 = esrc[p + 1];
    float n0 = enorm[p], n1 = enorm[p + 1];
    const float* x0 = xw + (size_t)s0 * 128;
    const float* x1 = xw + (size_t)s1 * 128;
    a0 += n0 * x0[lane];
    a1 += n0 * x0[lane + 64];
    a0 += n1 * x1[lane];
    a1 += n1 * x1[lane + 64];
  }
  if (p < e) {
    int s0 = esrc[p];
    float n0 = enorm[p];
    const float* x0 = xw + (size_t)s0 * 128;
    a0 += n0 * x0[lane];
    a1 += n0 * x0[lane + 64];
  }
  float d = dis[node];
  const float* xs = xw + (size_t)node * 128;
  a0 += d * d * xs[lane];
  a1 += d * d * xs[lane + 64];
  a0 = fmaxf(a0 + bconv[lane], 0.f);
  a1 = fmaxf(a1 + bconv[lane + 64], 0.f);
  out[(size_t)node * 128 + lane] = a0;
  out[(size_t)node * 128 + 64 + lane] = a1;
}

__global__ __launch_bounds__(256) void k_gstart(const int* __restrict__ batch, int n,
                                                int* __restrict__ gstart) {
  int g = threadIdx.x;
  if (g > 128) return;
  int lo = 0, hi = n;
  while (lo < hi) {
    int mid = (lo + hi) >> 1;
    if (batch[mid] < g) lo = mid + 1; else hi = mid;
  }
  gstart[g] = lo;
}

// node-parallel pool: 64 rows per block, register-accumulate along sorted
// batch, one atomicAdd per (thread, segment-change). hg must be pre-zeroed.
__global__ __launch_bounds__(256) void k_pool(const float* __restrict__ h,
                                              const int* __restrict__ batch,
                                              float* __restrict__ hg, int n) {
  int c = threadIdx.x & 127;
  int half = threadIdx.x >> 7;
  int r0 = blockIdx.x * 64;
  int rend = r0 + 64 < n ? r0 + 64 : n;
  float acc = 0.f;
  int cur = -1;
  for (int r = r0 + half; r < rend; r += 2) {
    int g = batch[r];
    if (g != cur) {
      if (cur >= 0) atomicAdd(&hg[cur * 128 + c], acc);
      cur = g;
      acc = 0.f;
    }
    acc += h[(size_t)r * 128 + c];
  }
  if (cur >= 0) atomicAdd(&hg[cur * 128 + c], acc);
}

// final: BN(bn_hid) on hg2, @ w_cls + b_cls, row log_softmax. 1 wave / graph.
__global__ __launch_bounds__(64) void k_final(const float* __restrict__ hg2,
                                              const float* __restrict__ sums,
                                              const float* __restrict__ g,
                                              const float* __restrict__ b,
                                              const float* __restrict__ w_cls,
                                              const float* __restrict__ b_cls,
                                              float* __restrict__ out) {
  int gid = blockIdx.x;
  int l = threadIdx.x;
  float m0 = sums[l] * (1.f / 128.f);
  float v0 = sums[128 + l] * (1.f / 128.f) - m0 * m0;
  float A0 = g[l] * rsqrtf(v0 + EPS);
  float B0 = b[l] - A0 * m0;
  float m1 = sums[l + 64] * (1.f / 128.f);
  float v1 = sums[128 + l + 64] * (1.f / 128.f) - m1 * m1;
  float A1 = g[l + 64] * rsqrtf(v1 + EPS);
  float B1 = b[l + 64] - A1 * m1;
  float a0 = A0 * hg2[gid * 128 + l] + B0;
  float a1 = A1 * hg2[gid * 128 + 64 + l] + B1;
  float logit[10];
#pragma unroll
  for (int c = 0; c < 10; ++c) {
    float p = a0 * w_cls[l * 10 + c] + a1 * w_cls[(l + 64) * 10 + c];
#pragma unroll
    for (int off = 32; off; off >>= 1) p += __shfl_xor(p, off, 64);
    logit[c] = p + b_cls[c];
  }
  if (l == 0) {
    float mx = logit[0];
#pragma unroll
    for (int c = 1; c < 10; ++c) mx = fmaxf(mx, logit[c]);
    float se = 0.f;
#pragma unroll
    for (int c = 0; c < 10; ++c) se += expf(logit[c] - mx);
    float lse = mx + logf(se);
#pragma unroll
    for (int c = 0; c < 10; ++c) out[gid * 10 + c] = logit[c] - lse;
  }
}

static inline char* alignp(char* p, size_t a) {
  return (char*)(((uintptr_t)p + a - 1) & ~(a - 1));
}

extern "C" void kernel_launch(void* const* d_in, const int* in_sizes, int n_in,
                              void* d_out, int out_size, void* d_ws, size_t ws_size,
                              hipStream_t stream) {
  const float* x         = (const float*)d_in[0];
  const int*   ei        = (const int*)d_in[1];
  const int*   batch     = (const int*)d_in[2];
  const float* bn_feat_g = (const float*)d_in[3];
  const float* bn_feat_b = (const float*)d_in[4];
  const float* w_feat    = (const float*)d_in[5];
  const float* bn_conv_g = (const float*)d_in[6];
  const float* bn_conv_b = (const float*)d_in[7];
  const float* w_conv    = (const float*)d_in[8];
  const float* b_conv    = (const float*)d_in[9];
  const float* bn_fc_g   = (const float*)d_in[10];
  const float* bn_fc_b   = (const float*)d_in[11];
  const float* w_fc      = (const float*)d_in[12];
  const float* b_fc      = (const float*)d_in[13];
  const float* bn_hid_g  = (const float*)d_in[14];
  const float* bn_hid_b  = (const float*)d_in[15];
  const float* w_cls     = (const float*)d_in[16];
  const float* b_cls     = (const float*)d_in[17];
  float* out = (float*)d_out;

  const int N = in_sizes[0] / 128;
  const int E = in_sizes[1] / 2;
  const int* src = ei;
  const int* dst = ei + E;

  char* p = (char*)d_ws;
  auto carve = [&](size_t bytes) {
    char* q = alignp(p, 256);
    p = q + bytes;
    return q;
  };
  float* dis    = (float*)carve((size_t)N * 4);
  int*   deg    = (int*)carve((size_t)2 * N * 4);  // deg | cnt adjacent
  int*   cnt    = deg + N;
  int*   rowp   = (int*)carve((size_t)(N + 1) * 4);
  int*   cursor = (int*)carve((size_t)N * 4);
  int*   bsum   = (int*)carve(256 * 4);
  int*   esrc   = (int*)carve((size_t)E * 4);
  float* enorm  = (float*)carve((size_t)E * 4);
  float* sums   = (float*)carve(256 * 4);
  float* Wf     = (float*)carve(16384 * 4);
  float* biasf  = (float*)carve(128 * 4);
  float* h      = (float*)carve((size_t)N * 128 * 4);
  float* xw     = (float*)carve((size_t)N * 128 * 4);
  float* hg     = (float*)carve(16384 * 4);
  float* hg2    = (float*)carve(16384 * 4);
  int*   gstart = (int*)carve(129 * 4);

  const int EB = (E + 255) / 256;
  const int NB = (N + 255) / 256;
  const int MMB = (N + 63) / 64;
  const int PB = (N + 3) / 4;
  const int SB = (N + 1023) / 1024;  // scan blocks (49 for N=50000)

  // --- graph preprocessing (same every launch) ---
  hipMemsetAsync(deg, 0, (size_t)2 * N * 4, stream);
  k_deg_hist<<<EB, 256, 0, stream>>>(src, dst, E, deg, cnt);
  k_dis<<<NB, 256, 0, stream>>>(deg, dis, N);
  k_scan1<<<SB, 256, 0, stream>>>(cnt, N, rowp, bsum);
  k_scan2<<<1, 64, 0, stream>>>(bsum, SB);
  k_scan3<<<SB, 256, 0, stream>>>(rowp, cursor, bsum, N);
  k_scatter<<<EB, 256, 0, stream>>>(src, dst, E, dis, cursor, esrc, enorm);
  k_gstart<<<1, 256, 0, stream>>>(batch, N, gstart);

  // --- feat layer: h = relu(BN(x) @ w_feat) ---
  hipMemsetAsync(sums, 0, 256 * 4, stream);
  k_stats<<<256, 256, 0, stream>>>(x, N, sums);
  k_fold<<<1, 128, 0, stream>>>(bn_feat_g, bn_feat_b, w_feat, sums, 1.f / N,
                                nullptr, Wf, biasf);
  k_matmul<<<MMB, 256, 0, stream>>>(x, Wf, biasf, h, N, 1);

  // --- 3 conv layers ---
  for (int i = 0; i < 3; ++i) {
    hipMemsetAsync(sums, 0, 256 * 4, stream);
    k_stats<<<256, 256, 0, stream>>>(h, N, sums);
    k_fold<<<1, 128, 0, stream>>>(bn_conv_g + i * 128, bn_conv_b + i * 128,
                                  w_conv + (size_t)i * 16384, sums, 1.f / N,
                                  nullptr, Wf, biasf);
    k_matmul<<<MMB, 256, 0, stream>>>(h, Wf, biasf, xw, N, 0);
    k_prop<<<PB, 256, 0, stream>>>(xw, rowp, esrc, enorm, dis, b_conv + i * 128,
                                   h, N);
  }

  // --- pool + head ---
  hipMemsetAsync(hg, 0, 16384 * 4, stream);
  k_pool<<<(N + 63) / 64, 256, 0, stream>>>(h, batch, hg, N);

  hipMemsetAsync(sums, 0, 256 * 4, stream);
  k_stats<<<16, 256, 0, stream>>>(hg, 128, sums);
  k_fold<<<1, 128, 0, stream>>>(bn_fc_g, bn_fc_b, w_fc, sums, 1.f / 128.f, b_fc,
                                Wf, biasf);
  k_matmul<<<2, 256, 0, stream>>>(hg, Wf, biasf, hg2, 128, 1);

  hipMemsetAsync(sums, 0, 256 * 4, stream);
  k_stats<<<16, 256, 0, stream>>>(hg2, 128, sums);
  k_final<<<128, 64, 0, stream>>>(hg2, sums, bn_hid_g, bn_hid_b, w_cls, b_cls,
                                  out);
}

// Round 3
// 535.812 us; speedup vs baseline: 1.7143x; 1.4175x over previous
//
#include <hip/hip_runtime.h>
#include <hip/hip_bf16.h>
#include <math.h>
#include <stdint.h>

// ---------------------------------------------------------------------------
// GCNNet forward, MI355X.
// R3: bf16 datapath for node features. 4 big matmuls -> MFMA 16x16x32 bf16
//     (fp32 version was 55us each: 1 block/CU, 4-way LDS bank conflicts).
//     BN-fold emits transposed bf16 weights. prop/stats/pool read bf16
//     (halves gather traffic). Head (128x128) stays fp32.
// ---------------------------------------------------------------------------

#define EPS 1e-5f

typedef __attribute__((ext_vector_type(8))) short bf16x8;
typedef __attribute__((ext_vector_type(4))) float f32x4;

__global__ __launch_bounds__(256) void k_deg_hist(const int* __restrict__ src,
                                                  const int* __restrict__ dst,
                                                  int e, int* __restrict__ deg,
                                                  int* __restrict__ cnt) {
  int i = blockIdx.x * 256 + threadIdx.x;
  if (i < e) {
    atomicAdd(&deg[src[i]], 1);
    atomicAdd(&cnt[dst[i]], 1);
  }
}

__global__ __launch_bounds__(256) void k_dis(const int* __restrict__ deg,
                                             float* __restrict__ dis, int n) {
  int i = blockIdx.x * 256 + threadIdx.x;
  if (i < n) dis[i] = rsqrtf((float)(deg[i] + 1));  // +1 self loop
}

// --- 3-phase scan ---
__global__ __launch_bounds__(256) void k_scan1(const int* __restrict__ cnt, int n,
                                               int* __restrict__ rowp,
                                               int* __restrict__ bsum) {
  __shared__ int ls[256];
  int base = blockIdx.x * 1024;
  int t = threadIdx.x;
  int idx = base + t * 4;
  int v[4];
#pragma unroll
  for (int j = 0; j < 4; ++j) v[j] = (idx + j < n) ? cnt[idx + j] : 0;
  int tot = v[0] + v[1] + v[2] + v[3];
  v[1] += v[0]; v[2] += v[1]; v[3] += v[2];
  ls[t] = tot;
  __syncthreads();
  for (int off = 1; off < 256; off <<= 1) {
    int add = (t >= off) ? ls[t - off] : 0;
    __syncthreads();
    ls[t] += add;
    __syncthreads();
  }
  int prefix = (t > 0) ? ls[t - 1] : 0;
#pragma unroll
  for (int j = 0; j < 4; ++j)
    if (idx + j < n) rowp[idx + j + 1] = v[j] + prefix;
  if (t == 255) bsum[blockIdx.x] = ls[255];
}

__global__ __launch_bounds__(64) void k_scan2(int* __restrict__ bsum, int nb) {
  int t = threadIdx.x;
  int orig = (t < nb) ? bsum[t] : 0;
  int v = orig;
  for (int off = 1; off < 64; off <<= 1) {
    int u = __shfl_up(v, off, 64);
    if (t >= off) v += u;
  }
  if (t < nb) bsum[t] = v - orig;  // exclusive
}

__global__ __launch_bounds__(256) void k_scan3(int* __restrict__ rowp,
                                               int* __restrict__ cursor,
                                               const int* __restrict__ bsum, int n) {
  int base = blockIdx.x * 1024;
  int off = bsum[blockIdx.x];
  int t = threadIdx.x;
#pragma unroll
  for (int j = 0; j < 4; ++j) {
    int i = base + t + j * 256;
    if (i < n) {
      int val = rowp[i + 1] + off;
      rowp[i + 1] = val;
      if (i + 1 < n) cursor[i + 1] = val;
    }
  }
  if (blockIdx.x == 0 && t == 0) { rowp[0] = 0; cursor[0] = 0; }
}

__global__ __launch_bounds__(256) void k_scatter(const int* __restrict__ src,
                                                 const int* __restrict__ dst, int e,
                                                 const float* __restrict__ dis,
                                                 int* __restrict__ cursor,
                                                 int* __restrict__ esrc,
                                                 float* __restrict__ enorm) {
  int i = blockIdx.x * 256 + threadIdx.x;
  if (i < e) {
    int s = src[i], d = dst[i];
    int p = atomicAdd(&cursor[d], 1);
    esrc[p] = s;
    enorm[p] = dis[s] * dis[d];
  }
}

// fp32 -> bf16 cast of x
__global__ __launch_bounds__(256) void k_cast(const float* __restrict__ x,
                                              __hip_bfloat16* __restrict__ xb,
                                              int total4) {
  int i = blockIdx.x * 256 + threadIdx.x;
  if (i < total4) {
    float4 v = ((const float4*)x)[i];
    __hip_bfloat162* d = (__hip_bfloat162*)xb + i * 2;
    d[0] = __hip_bfloat162{__float2bfloat16(v.x), __float2bfloat16(v.y)};
    d[1] = __hip_bfloat162{__float2bfloat16(v.z), __float2bfloat16(v.w)};
  }
}

// column sums / sumsq, fp32 input (x, hg, hg2)
__global__ __launch_bounds__(256) void k_stats(const float* __restrict__ h, int n,
                                               float* __restrict__ sums) {
  int c = threadIdx.x & 127;
  int half = threadIdx.x >> 7;
  float s = 0.f, s2 = 0.f;
  for (int r = blockIdx.x * 2 + half; r < n; r += gridDim.x * 2) {
    float v = h[(size_t)r * 128 + c];
    s += v;
    s2 += v * v;
  }
  __shared__ float ls[256];
  __shared__ float ls2[256];
  ls[threadIdx.x] = s;
  ls2[threadIdx.x] = s2;
  __syncthreads();
  if (half == 0) {
    atomicAdd(&sums[c], ls[c] + ls[c + 128]);
    atomicAdd(&sums[128 + c], ls2[c] + ls2[c + 128]);
  }
}

// column sums / sumsq, bf16 input (h between conv layers)
__global__ __launch_bounds__(256) void k_stats_bf16(const __hip_bfloat16* __restrict__ h,
                                                    int n, float* __restrict__ sums) {
  int cp = threadIdx.x & 63;   // column pair
  int rg = threadIdx.x >> 6;   // 0..3
  const __hip_bfloat162* h2 = (const __hip_bfloat162*)h;
  float s0 = 0.f, s20 = 0.f, s1 = 0.f, s21 = 0.f;
  for (int r = blockIdx.x * 4 + rg; r < n; r += gridDim.x * 4) {
    __hip_bfloat162 v = h2[(size_t)r * 64 + cp];
    float a = __bfloat162float(v.x), b = __bfloat162float(v.y);
    s0 += a; s20 += a * a;
    s1 += b; s21 += b * b;
  }
  __shared__ float ls[512], ls2[512];
  ls[rg * 128 + 2 * cp] = s0;  ls[rg * 128 + 2 * cp + 1] = s1;
  ls2[rg * 128 + 2 * cp] = s20; ls2[rg * 128 + 2 * cp + 1] = s21;
  __syncthreads();
  if (threadIdx.x < 128) {
    int c = threadIdx.x;
    float a = ls[c] + ls[128 + c] + ls[256 + c] + ls[384 + c];
    float b = ls2[c] + ls2[128 + c] + ls2[256 + c] + ls2[384 + c];
    atomicAdd(&sums[c], a);
    atomicAdd(&sums[128 + c], b);
  }
}

// fold BN into W, emit TRANSPOSED bf16 weight: WfT[j][k] = A[k]*W[k][j]
// biasf[j] = sum_k B[k]*W[k][j]
__global__ __launch_bounds__(128) void k_foldT(const float* __restrict__ g,
                                               const float* __restrict__ b,
                                               const float* __restrict__ W,
                                               const float* __restrict__ sums,
                                               float inv_n,
                                               __hip_bfloat16* __restrict__ WfT,
                                               float* __restrict__ biasf) {
  __shared__ float A[128], B[128];
  int t = threadIdx.x;
  float m = sums[t] * inv_n;
  float v = sums[128 + t] * inv_n - m * m;
  float rs = rsqrtf(v + EPS);
  float a = g[t] * rs;
  A[t] = a;
  B[t] = b[t] - a * m;
  __syncthreads();
  float bias = 0.f;
  for (int k = 0; k < 128; ++k) {
    float w = W[k * 128 + t];   // coalesced across t
    bias += B[k] * w;
    WfT[t * 128 + k] = __float2bfloat16(A[k] * w);  // row t of WfT
  }
  biasf[t] = bias;
}

// fp32 fold (fc head): Wf[k][j] = A[k]*W[k][j], biasf += extra
__global__ __launch_bounds__(128) void k_fold(const float* __restrict__ g,
                                              const float* __restrict__ b,
                                              const float* __restrict__ W,
                                              const float* __restrict__ sums,
                                              float inv_n,
                                              const float* __restrict__ extra,
                                              float* __restrict__ Wf,
                                              float* __restrict__ biasf) {
  __shared__ float A[128], B[128];
  int t = threadIdx.x;
  float m = sums[t] * inv_n;
  float v = sums[128 + t] * inv_n - m * m;
  float rs = rsqrtf(v + EPS);
  float a = g[t] * rs;
  A[t] = a;
  B[t] = b[t] - a * m;
  __syncthreads();
  float bias = extra ? extra[t] : 0.f;
  for (int k = 0; k < 128; ++k) {
    float w = W[k * 128 + t];
    Wf[k * 128 + t] = A[k] * w;
    bias += B[k] * w;
  }
  biasf[t] = bias;
}

// MFMA bf16 matmul: out[n,128](bf16) = in[n,128](bf16) @ WfT^T + biasf
// block = 256 thr = 4 waves, 128-row tile. LDS: A + B, stride 136 (pad 8).
#define LDP 136
__global__ __launch_bounds__(256) void k_matmul_bf16(
    const __hip_bfloat16* __restrict__ in, const __hip_bfloat16* __restrict__ WfT,
    const float* __restrict__ biasf, __hip_bfloat16* __restrict__ out, int n,
    int relu) {
  __shared__ short sA[128 * LDP];
  __shared__ short sB[128 * LDP];
  int tid = threadIdx.x;
  int r0 = blockIdx.x * 128;
  // stage A (rows r0..r0+127) and B=WfT, 16B chunks
  const uint4* in4 = (const uint4*)in;    // 16 chunks per row
  const uint4* wt4 = (const uint4*)WfT;
#pragma unroll
  for (int i = 0; i < 8; ++i) {
    int c = tid + i * 256;                // 0..2047
    int r = c >> 4, k8 = c & 15;
    int gr = r0 + r;
    uint4 v = make_uint4(0, 0, 0, 0);
    if (gr < n) v = in4[(size_t)gr * 16 + k8];
    *(uint4*)&sA[r * LDP + k8 * 8] = v;
    *(uint4*)&sB[r * LDP + k8 * 8] = wt4[c];
  }
  __syncthreads();
  int w = tid >> 6, lane = tid & 63;
  int q = lane >> 4, ln = lane & 15;
  f32x4 acc[2][8];
#pragma unroll
  for (int mt = 0; mt < 2; ++mt)
#pragma unroll
    for (int nt = 0; nt < 8; ++nt) acc[mt][nt] = (f32x4)0.f;
#pragma unroll
  for (int s = 0; s < 4; ++s) {
    int ko = s * 32 + q * 8;
    bf16x8 a0 = *(bf16x8*)&sA[(w * 32 + ln) * LDP + ko];
    bf16x8 a1 = *(bf16x8*)&sA[(w * 32 + 16 + ln) * LDP + ko];
#pragma unroll
    for (int nt = 0; nt < 8; ++nt) {
      bf16x8 bb = *(bf16x8*)&sB[(nt * 16 + ln) * LDP + ko];
      acc[0][nt] = __builtin_amdgcn_mfma_f32_16x16x32_bf16(a0, bb, acc[0][nt], 0, 0, 0);
      acc[1][nt] = __builtin_amdgcn_mfma_f32_16x16x32_bf16(a1, bb, acc[1][nt], 0, 0, 0);
    }
  }
  float bias8[8];
#pragma unroll
  for (int nt = 0; nt < 8; ++nt) bias8[nt] = biasf[nt * 16 + ln];
#pragma unroll
  for (int mt = 0; mt < 2; ++mt) {
    int rbase = r0 + w * 32 + mt * 16 + q * 4;
#pragma unroll
    for (int r = 0; r < 4; ++r) {
      int gr = rbase + r;
      if (gr < n) {
#pragma unroll
        for (int nt = 0; nt < 8; ++nt) {
          float v = acc[mt][nt][r] + bias8[nt];
          if (relu) v = fmaxf(v, 0.f);
          out[(size_t)gr * 128 + nt * 16 + ln] = __float2bfloat16(v);
        }
      }
    }
  }
}

// fp32 matmul for the head (hg[128,128] @ Wf + bias)
__global__ __launch_bounds__(256) void k_matmul_f32(const float* __restrict__ in,
                                                    const float* __restrict__ W,
                                                    const float* __restrict__ bias,
                                                    float* __restrict__ out, int n,
                                                    int relu) {
  __shared__ float sW[128 * 128];
  __shared__ float sH[64 * 129];
  int tid = threadIdx.x;
  int row0 = blockIdx.x * 64;
  const float4* W4 = (const float4*)W;
  float4* sW4 = (float4*)sW;
#pragma unroll
  for (int i = 0; i < 16; ++i) sW4[tid + i * 256] = W4[tid + i * 256];
  for (int i = tid; i < 64 * 32; i += 256) {
    int r = i >> 5, c4 = i & 31;
    int gr = row0 + r;
    float4 v = make_float4(0.f, 0.f, 0.f, 0.f);
    if (gr < n) v = ((const float4*)(in + (size_t)gr * 128))[c4];
    float* dp = &sH[r * 129 + (c4 << 2)];
    dp[0] = v.x; dp[1] = v.y; dp[2] = v.z; dp[3] = v.w;
  }
  __syncthreads();
  int tx = tid & 15, ty = tid >> 4;
  int col0 = tx * 8;
  float acc[4][8];
#pragma unroll
  for (int i = 0; i < 4; ++i)
#pragma unroll
    for (int j = 0; j < 8; ++j) acc[i][j] = bias[col0 + j];
  for (int k = 0; k < 128; ++k) {
    float hv[4];
#pragma unroll
    for (int i = 0; i < 4; ++i) hv[i] = sH[(ty * 4 + i) * 129 + k];
    const float* wr = &sW[k * 128 + col0];
    float4 wa = *(const float4*)wr;
    float4 wb = *(const float4*)(wr + 4);
    float wv[8] = {wa.x, wa.y, wa.z, wa.w, wb.x, wb.y, wb.z, wb.w};
#pragma unroll
    for (int i = 0; i < 4; ++i)
#pragma unroll
      for (int j = 0; j < 8; ++j) acc[i][j] += hv[i] * wv[j];
  }
#pragma unroll
  for (int i = 0; i < 4; ++i) {
    int gr = row0 + ty * 4 + i;
    if (gr < n) {
      float o[8];
#pragma unroll
      for (int j = 0; j < 8; ++j)
        o[j] = relu ? fmaxf(acc[i][j], 0.f) : acc[i][j];
      float4* dp = (float4*)(out + (size_t)gr * 128 + col0);
      dp[0] = make_float4(o[0], o[1], o[2], o[3]);
      dp[1] = make_float4(o[4], o[5], o[6], o[7]);
    }
  }
}

// CSR propagate on bf16: out[d] = relu(sum norm*xw[src] + dis^2*xw[d] + bconv)
// one wave per node; lane handles column pair {2*lane, 2*lane+1}
__global__ __launch_bounds__(256) void k_prop(const __hip_bfloat16* __restrict__ xw,
                                              const int* __restrict__ row_ptr,
                                              const int* __restrict__ esrc,
                                              const float* __restrict__ enorm,
                                              const float* __restrict__ dis,
                                              const float* __restrict__ bconv,
                                              __hip_bfloat16* __restrict__ out,
                                              int n) {
  int wave = threadIdx.x >> 6;
  int lane = threadIdx.x & 63;
  int node = blockIdx.x * 4 + wave;
  if (node >= n) return;
  const __hip_bfloat162* x2 = (const __hip_bfloat162*)xw;
  int s = row_ptr[node], e = row_ptr[node + 1];
  float a0 = 0.f, a1 = 0.f;
  int p = s;
  for (; p + 1 < e; p += 2) {
    int s0 = esrc[p], s1 = esrc[p + 1];
    float n0 = enorm[p], n1 = enorm[p + 1];
    __hip_bfloat162 v0 = x2[(size_t)s0 * 64 + lane];
    __hip_bfloat162 v1 = x2[(size_t)s1 * 64 + lane];
    a0 += n0 * __bfloat162float(v0.x) + n1 * __bfloat162float(v1.x);
    a1 += n0 * __bfloat162float(v0.y) + n1 * __bfloat162float(v1.y);
  }
  if (p < e) {
    int s0 = esrc[p];
    float n0 = enorm[p];
    __hip_bfloat162 v0 = x2[(size_t)s0 * 64 + lane];
    a0 += n0 * __bfloat162float(v0.x);
    a1 += n0 * __bfloat162float(v0.y);
  }
  float d = dis[node];
  __hip_bfloat162 vs = x2[(size_t)node * 64 + lane];
  a0 += d * d * __bfloat162float(vs.x);
  a1 += d * d * __bfloat162float(vs.y);
  a0 = fmaxf(a0 + bconv[2 * lane], 0.f);
  a1 = fmaxf(a1 + bconv[2 * lane + 1], 0.f);
  __hip_bfloat162* o2 = (__hip_bfloat162*)out;
  o2[(size_t)node * 64 + lane] =
      __hip_bfloat162{__float2bfloat16(a0), __float2bfloat16(a1)};
}

// node-parallel pool over bf16 h -> fp32 hg (pre-zeroed)
__global__ __launch_bounds__(256) void k_pool(const __hip_bfloat16* __restrict__ h,
                                              const int* __restrict__ batch,
                                              float* __restrict__ hg, int n) {
  int c = threadIdx.x & 127;
  int half = threadIdx.x >> 7;
  int r0 = blockIdx.x * 64;
  int rend = r0 + 64 < n ? r0 + 64 : n;
  float acc = 0.f;
  int cur = -1;
  for (int r = r0 + half; r < rend; r += 2) {
    int g = batch[r];
    if (g != cur) {
      if (cur >= 0) atomicAdd(&hg[cur * 128 + c], acc);
      cur = g;
      acc = 0.f;
    }
    acc += __bfloat162float(h[(size_t)r * 128 + c]);
  }
  if (cur >= 0) atomicAdd(&hg[cur * 128 + c], acc);
}

// final: BN(bn_hid) on hg2, @ w_cls + b_cls, log_softmax. 1 wave / graph.
__global__ __launch_bounds__(64) void k_final(const float* __restrict__ hg2,
                                              const float* __restrict__ sums,
                                              const float* __restrict__ g,
                                              const float* __restrict__ b,
                                              const float* __restrict__ w_cls,
                                              const float* __restrict__ b_cls,
                                              float* __restrict__ out) {
  int gid = blockIdx.x;
  int l = threadIdx.x;
  float m0 = sums[l] * (1.f / 128.f);
  float v0 = sums[128 + l] * (1.f / 128.f) - m0 * m0;
  float A0 = g[l] * rsqrtf(v0 + EPS);
  float B0 = b[l] - A0 * m0;
  float m1 = sums[l + 64] * (1.f / 128.f);
  float v1 = sums[128 + l + 64] * (1.f / 128.f) - m1 * m1;
  float A1 = g[l + 64] * rsqrtf(v1 + EPS);
  float B1 = b[l + 64] - A1 * m1;
  float a0 = A0 * hg2[gid * 128 + l] + B0;
  float a1 = A1 * hg2[gid * 128 + 64 + l] + B1;
  float logit[10];
#pragma unroll
  for (int c = 0; c < 10; ++c) {
    float p = a0 * w_cls[l * 10 + c] + a1 * w_cls[(l + 64) * 10 + c];
#pragma unroll
    for (int off = 32; off; off >>= 1) p += __shfl_xor(p, off, 64);
    logit[c] = p + b_cls[c];
  }
  if (l == 0) {
    float mx = logit[0];
#pragma unroll
    for (int c = 1; c < 10; ++c) mx = fmaxf(mx, logit[c]);
    float se = 0.f;
#pragma unroll
    for (int c = 0; c < 10; ++c) se += expf(logit[c] - mx);
    float lse = mx + logf(se);
#pragma unroll
    for (int c = 0; c < 10; ++c) out[gid * 10 + c] = logit[c] - lse;
  }
}

static inline char* alignp(char* p, size_t a) {
  return (char*)(((uintptr_t)p + a - 1) & ~(a - 1));
}

extern "C" void kernel_launch(void* const* d_in, const int* in_sizes, int n_in,
                              void* d_out, int out_size, void* d_ws, size_t ws_size,
                              hipStream_t stream) {
  const float* x         = (const float*)d_in[0];
  const int*   ei        = (const int*)d_in[1];
  const int*   batch     = (const int*)d_in[2];
  const float* bn_feat_g = (const float*)d_in[3];
  const float* bn_feat_b = (const float*)d_in[4];
  const float* w_feat    = (const float*)d_in[5];
  const float* bn_conv_g = (const float*)d_in[6];
  const float* bn_conv_b = (const float*)d_in[7];
  const float* w_conv    = (const float*)d_in[8];
  const float* b_conv    = (const float*)d_in[9];
  const float* bn_fc_g   = (const float*)d_in[10];
  const float* bn_fc_b   = (const float*)d_in[11];
  const float* w_fc      = (const float*)d_in[12];
  const float* b_fc      = (const float*)d_in[13];
  const float* bn_hid_g  = (const float*)d_in[14];
  const float* bn_hid_b  = (const float*)d_in[15];
  const float* w_cls     = (const float*)d_in[16];
  const float* b_cls     = (const float*)d_in[17];
  float* out = (float*)d_out;

  const int N = in_sizes[0] / 128;
  const int E = in_sizes[1] / 2;
  const int* src = ei;
  const int* dst = ei + E;

  char* p = (char*)d_ws;
  auto carve = [&](size_t bytes) {
    char* q = alignp(p, 256);
    p = q + bytes;
    return q;
  };
  float* dis    = (float*)carve((size_t)N * 4);
  int*   deg    = (int*)carve((size_t)2 * N * 4);
  int*   cnt    = deg + N;
  int*   rowp   = (int*)carve((size_t)(N + 1) * 4);
  int*   cursor = (int*)carve((size_t)N * 4);
  int*   bsum   = (int*)carve(256 * 4);
  int*   esrc   = (int*)carve((size_t)E * 4);
  float* enorm  = (float*)carve((size_t)E * 4);
  float* sums   = (float*)carve(256 * 4);
  float* Wf     = (float*)carve(16384 * 4);       // fp32 fold (fc)
  __hip_bfloat16* WfT = (__hip_bfloat16*)carve(16384 * 2);
  float* biasf  = (float*)carve(128 * 4);
  __hip_bfloat16* xb = (__hip_bfloat16*)carve((size_t)N * 128 * 2);
  __hip_bfloat16* h  = (__hip_bfloat16*)carve((size_t)N * 128 * 2);
  __hip_bfloat16* xw = (__hip_bfloat16*)carve((size_t)N * 128 * 2);
  float* hg     = (float*)carve(16384 * 4);
  float* hg2    = (float*)carve(16384 * 4);

  const int EB = (E + 255) / 256;
  const int NB = (N + 255) / 256;
  const int MMB = (N + 127) / 128;
  const int PB = (N + 3) / 4;
  const int SB = (N + 1023) / 1024;

  // --- graph preprocessing ---
  hipMemsetAsync(deg, 0, (size_t)2 * N * 4, stream);
  k_deg_hist<<<EB, 256, 0, stream>>>(src, dst, E, deg, cnt);
  k_dis<<<NB, 256, 0, stream>>>(deg, dis, N);
  k_scan1<<<SB, 256, 0, stream>>>(cnt, N, rowp, bsum);
  k_scan2<<<1, 64, 0, stream>>>(bsum, SB);
  k_scan3<<<SB, 256, 0, stream>>>(rowp, cursor, bsum, N);
  k_scatter<<<EB, 256, 0, stream>>>(src, dst, E, dis, cursor, esrc, enorm);
  k_cast<<<(N * 128 / 4 + 255) / 256, 256, 0, stream>>>(x, xb, N * 128 / 4);

  // --- feat layer: h = relu(BN(x) @ w_feat) ---
  hipMemsetAsync(sums, 0, 256 * 4, stream);
  k_stats<<<256, 256, 0, stream>>>(x, N, sums);
  k_foldT<<<1, 128, 0, stream>>>(bn_feat_g, bn_feat_b, w_feat, sums, 1.f / N,
                                 WfT, biasf);
  k_matmul_bf16<<<MMB, 256, 0, stream>>>(xb, WfT, biasf, h, N, 1);

  // --- 3 conv layers ---
  for (int i = 0; i < 3; ++i) {
    hipMemsetAsync(sums, 0, 256 * 4, stream);
    k_stats_bf16<<<256, 256, 0, stream>>>(h, N, sums);
    k_foldT<<<1, 128, 0, stream>>>(bn_conv_g + i * 128, bn_conv_b + i * 128,
                                   w_conv + (size_t)i * 16384, sums, 1.f / N,
                                   WfT, biasf);
    k_matmul_bf16<<<MMB, 256, 0, stream>>>(h, WfT, biasf, xw, N, 0);
    k_prop<<<PB, 256, 0, stream>>>(xw, rowp, esrc, enorm, dis, b_conv + i * 128,
                                   h, N);
  }

  // --- pool + head (fp32) ---
  hipMemsetAsync(hg, 0, 16384 * 4, stream);
  k_pool<<<(N + 63) / 64, 256, 0, stream>>>(h, batch, hg, N);

  hipMemsetAsync(sums, 0, 256 * 4, stream);
  k_stats<<<16, 256, 0, stream>>>(hg, 128, sums);
  k_fold<<<1, 128, 0, stream>>>(bn_fc_g, bn_fc_b, w_fc, sums, 1.f / 128.f, b_fc,
                                Wf, biasf);
  k_matmul_f32<<<2, 256, 0, stream>>>(hg, Wf, biasf, hg2, 128, 1);

  hipMemsetAsync(sums, 0, 256 * 4, stream);
  k_stats<<<16, 256, 0, stream>>>(hg2, 128, sums);
  k_final<<<128, 64, 0, stream>>>(hg2, sums, bn_hid_g, bn_hid_b, w_cls, b_cls,
                                  out);
}

// Round 4
// 449.717 us; speedup vs baseline: 2.0425x; 1.1914x over previous
//
#include <hip/hip_runtime.h>
#include <hip/hip_bf16.h>
#include <math.h>
#include <stdint.h>

// ---------------------------------------------------------------------------
// GCNNet forward, MI355X.
// R4: parallel BN-fold kernels (were single-block latency traps), fused
//     x-stats+cast, packed edge data (src,norm) int2, prop unroll-4,
//     single memset region, scan2 folded into scan3.
// ---------------------------------------------------------------------------

#define EPS 1e-5f

typedef __attribute__((ext_vector_type(8))) short bf16x8;
typedef __attribute__((ext_vector_type(4))) float f32x4;

__global__ __launch_bounds__(256) void k_deg_hist(const int* __restrict__ src,
                                                  const int* __restrict__ dst,
                                                  int e, int* __restrict__ deg,
                                                  int* __restrict__ cnt) {
  int i = blockIdx.x * 256 + threadIdx.x;
  if (i < e) {
    atomicAdd(&deg[src[i]], 1);
    atomicAdd(&cnt[dst[i]], 1);
  }
}

__global__ __launch_bounds__(256) void k_dis(const int* __restrict__ deg,
                                             float* __restrict__ dis, int n) {
  int i = blockIdx.x * 256 + threadIdx.x;
  if (i < n) dis[i] = rsqrtf((float)(deg[i] + 1));  // +1 self loop
}

// --- scan phase 1: block-local inclusive scan of cnt, block sums to bsum ---
__global__ __launch_bounds__(256) void k_scan1(const int* __restrict__ cnt, int n,
                                               int* __restrict__ rowp,
                                               int* __restrict__ bsum) {
  __shared__ int ls[256];
  int base = blockIdx.x * 1024;
  int t = threadIdx.x;
  int idx = base + t * 4;
  int v[4];
#pragma unroll
  for (int j = 0; j < 4; ++j) v[j] = (idx + j < n) ? cnt[idx + j] : 0;
  int tot = v[0] + v[1] + v[2] + v[3];
  v[1] += v[0]; v[2] += v[1]; v[3] += v[2];
  ls[t] = tot;
  __syncthreads();
  for (int off = 1; off < 256; off <<= 1) {
    int add = (t >= off) ? ls[t - off] : 0;
    __syncthreads();
    ls[t] += add;
    __syncthreads();
  }
  int prefix = (t > 0) ? ls[t - 1] : 0;
#pragma unroll
  for (int j = 0; j < 4; ++j)
    if (idx + j < n) rowp[idx + j + 1] = v[j] + prefix;
  if (t == 255) bsum[blockIdx.x] = ls[255];
}

// --- scan phase 2+3 fused: each block wave-scans bsum itself, adds offset,
//     also produces cursor[] = final rowp[] ---
__global__ __launch_bounds__(256) void k_scan3(int* __restrict__ rowp,
                                               int* __restrict__ cursor,
                                               const int* __restrict__ bsum,
                                               int n, int nb) {
  __shared__ int soff;
  int t = threadIdx.x;
  if (t < 64) {
    int orig = (t < nb) ? bsum[t] : 0;
    int v = orig;
    for (int off = 1; off < 64; off <<= 1) {
      int u = __shfl_up(v, off, 64);
      if (t >= off) v += u;
    }
    if (t == (int)blockIdx.x) soff = v - orig;  // exclusive prefix
  }
  __syncthreads();
  int off = soff;
  int base = blockIdx.x * 1024;
#pragma unroll
  for (int j = 0; j < 4; ++j) {
    int i = base + t + j * 256;
    if (i < n) {
      int val = rowp[i + 1] + off;
      rowp[i + 1] = val;
      if (i + 1 < n) cursor[i + 1] = val;
    }
  }
  if (blockIdx.x == 0 && t == 0) { rowp[0] = 0; cursor[0] = 0; }
}

// scatter edges into dst-sorted CSR; pack (src, norm) into one int2
__global__ __launch_bounds__(256) void k_scatter(const int* __restrict__ src,
                                                 const int* __restrict__ dst, int e,
                                                 const float* __restrict__ dis,
                                                 int* __restrict__ cursor,
                                                 int2* __restrict__ edat) {
  int i = blockIdx.x * 256 + threadIdx.x;
  if (i < e) {
    int s = src[i], d = dst[i];
    int p = atomicAdd(&cursor[d], 1);
    int2 ev;
    ev.x = s;
    ev.y = __float_as_int(dis[s] * dis[d]);
    edat[p] = ev;
  }
}

// fused: column stats of fp32 x AND cast to bf16 (one 25.6MB pass)
__global__ __launch_bounds__(256) void k_prep_x(const float* __restrict__ x,
                                                __hip_bfloat16* __restrict__ xb,
                                                int n, float* __restrict__ sums) {
  int c4 = threadIdx.x & 31;  // float4 column chunk
  int rg = threadIdx.x >> 5;  // 0..7
  float s[4] = {0, 0, 0, 0}, s2[4] = {0, 0, 0, 0};
  for (int r = blockIdx.x * 8 + rg; r < n; r += gridDim.x * 8) {
    float4 v = ((const float4*)x)[(size_t)r * 32 + c4];
    s[0] += v.x; s2[0] += v.x * v.x;
    s[1] += v.y; s2[1] += v.y * v.y;
    s[2] += v.z; s2[2] += v.z * v.z;
    s[3] += v.w; s2[3] += v.w * v.w;
    __hip_bfloat162* d = (__hip_bfloat162*)xb + (size_t)r * 64 + c4 * 2;
    d[0] = __hip_bfloat162{__float2bfloat16(v.x), __float2bfloat16(v.y)};
    d[1] = __hip_bfloat162{__float2bfloat16(v.z), __float2bfloat16(v.w)};
  }
  __shared__ float ls[1024], ls2[1024];
#pragma unroll
  for (int j = 0; j < 4; ++j) {
    ls[rg * 128 + c4 * 4 + j] = s[j];
    ls2[rg * 128 + c4 * 4 + j] = s2[j];
  }
  __syncthreads();
  if (threadIdx.x < 128) {
    int c = threadIdx.x;
    float a = 0.f, b = 0.f;
#pragma unroll
    for (int g = 0; g < 8; ++g) { a += ls[g * 128 + c]; b += ls2[g * 128 + c]; }
    atomicAdd(&sums[c], a);
    atomicAdd(&sums[128 + c], b);
  }
}

// column sums / sumsq, fp32 input (hg, hg2)
__global__ __launch_bounds__(256) void k_stats(const float* __restrict__ h, int n,
                                               float* __restrict__ sums) {
  int c = threadIdx.x & 127;
  int half = threadIdx.x >> 7;
  float s = 0.f, s2 = 0.f;
  for (int r = blockIdx.x * 2 + half; r < n; r += gridDim.x * 2) {
    float v = h[(size_t)r * 128 + c];
    s += v;
    s2 += v * v;
  }
  __shared__ float ls[256];
  __shared__ float ls2[256];
  ls[threadIdx.x] = s;
  ls2[threadIdx.x] = s2;
  __syncthreads();
  if (half == 0) {
    atomicAdd(&sums[c], ls[c] + ls[c + 128]);
    atomicAdd(&sums[128 + c], ls2[c] + ls2[c + 128]);
  }
}

// column sums / sumsq, bf16 input (h between conv layers)
__global__ __launch_bounds__(256) void k_stats_bf16(const __hip_bfloat16* __restrict__ h,
                                                    int n, float* __restrict__ sums) {
  int cp = threadIdx.x & 63;   // column pair
  int rg = threadIdx.x >> 6;   // 0..3
  const __hip_bfloat162* h2 = (const __hip_bfloat162*)h;
  float s0 = 0.f, s20 = 0.f, s1 = 0.f, s21 = 0.f;
  for (int r = blockIdx.x * 4 + rg; r < n; r += gridDim.x * 4) {
    __hip_bfloat162 v = h2[(size_t)r * 64 + cp];
    float a = __bfloat162float(v.x), b = __bfloat162float(v.y);
    s0 += a; s20 += a * a;
    s1 += b; s21 += b * b;
  }
  __shared__ float ls[512], ls2[512];
  ls[rg * 128 + 2 * cp] = s0;  ls[rg * 128 + 2 * cp + 1] = s1;
  ls2[rg * 128 + 2 * cp] = s20; ls2[rg * 128 + 2 * cp + 1] = s21;
  __syncthreads();
  if (threadIdx.x < 128) {
    int c = threadIdx.x;
    float a = ls[c] + ls[128 + c] + ls[256 + c] + ls[384 + c];
    float b = ls2[c] + ls2[128 + c] + ls2[256 + c] + ls2[384 + c];
    atomicAdd(&sums[c], a);
    atomicAdd(&sums[128 + c], b);
  }
}

// parallel BN-fold, transposed bf16 out: WfT[j][k] = A[k]*W[k][j].
// grid 16 blocks x 128 thr; block owns cols j in [b*8, b*8+8).
__global__ __launch_bounds__(128) void k_foldT(const float* __restrict__ g,
                                               const float* __restrict__ b,
                                               const float* __restrict__ W,
                                               const float* __restrict__ sums,
                                               float inv_n,
                                               __hip_bfloat16* __restrict__ WfT,
                                               float* __restrict__ biasf) {
  __shared__ float A[128], B[128];
  int t = threadIdx.x;
  float m = sums[t] * inv_n;
  float v = sums[128 + t] * inv_n - m * m;
  float rs = rsqrtf(v + EPS);
  float a = g[t] * rs;
  A[t] = a;
  B[t] = b[t] - a * m;
  __syncthreads();
  int jj = t >> 4, kc = t & 15;
  int j = blockIdx.x * 8 + jj;
  float bias = 0.f;
  union { short h[8]; uint4 q; } wr;
#pragma unroll
  for (int u = 0; u < 8; ++u) {
    int k = kc * 8 + u;
    float w = W[k * 128 + j];
    bias += B[k] * w;
    __hip_bfloat16 bw = __float2bfloat16(A[k] * w);
    wr.h[u] = *(short*)&bw;
  }
  *(uint4*)&WfT[j * 128 + kc * 8] = wr.q;
  // reduce bias over kc (lane bits 0..3)
#pragma unroll
  for (int off = 1; off < 16; off <<= 1) bias += __shfl_xor(bias, off, 64);
  if (kc == 0) biasf[j] = bias;
}

// parallel fp32 fold (fc head): Wf[k][j] = A[k]*W[k][j], bias += extra[j]
__global__ __launch_bounds__(128) void k_fold(const float* __restrict__ g,
                                              const float* __restrict__ b,
                                              const float* __restrict__ W,
                                              const float* __restrict__ sums,
                                              float inv_n,
                                              const float* __restrict__ extra,
                                              float* __restrict__ Wf,
                                              float* __restrict__ biasf) {
  __shared__ float A[128], B[128];
  int t = threadIdx.x;
  float m = sums[t] * inv_n;
  float v = sums[128 + t] * inv_n - m * m;
  float rs = rsqrtf(v + EPS);
  float a = g[t] * rs;
  A[t] = a;
  B[t] = b[t] - a * m;
  __syncthreads();
  int jj = t >> 4, kc = t & 15;
  int j = blockIdx.x * 8 + jj;
  float bias = 0.f;
#pragma unroll
  for (int u = 0; u < 8; ++u) {
    int k = kc * 8 + u;
    float w = W[k * 128 + j];
    bias += B[k] * w;
    Wf[k * 128 + j] = A[k] * w;
  }
#pragma unroll
  for (int off = 1; off < 16; off <<= 1) bias += __shfl_xor(bias, off, 64);
  if (kc == 0) biasf[j] = bias + extra[j];
}

// MFMA bf16 matmul: out[n,128](bf16) = in[n,128](bf16) @ WfT^T + biasf
#define LDP 136
__global__ __launch_bounds__(256) void k_matmul_bf16(
    const __hip_bfloat16* __restrict__ in, const __hip_bfloat16* __restrict__ WfT,
    const float* __restrict__ biasf, __hip_bfloat16* __restrict__ out, int n,
    int relu) {
  __shared__ short sA[128 * LDP];
  __shared__ short sB[128 * LDP];
  int tid = threadIdx.x;
  int r0 = blockIdx.x * 128;
  const uint4* in4 = (const uint4*)in;
  const uint4* wt4 = (const uint4*)WfT;
#pragma unroll
  for (int i = 0; i < 8; ++i) {
    int c = tid + i * 256;
    int r = c >> 4, k8 = c & 15;
    int gr = r0 + r;
    uint4 v = make_uint4(0, 0, 0, 0);
    if (gr < n) v = in4[(size_t)gr * 16 + k8];
    *(uint4*)&sA[r * LDP + k8 * 8] = v;
    *(uint4*)&sB[r * LDP + k8 * 8] = wt4[c];
  }
  __syncthreads();
  int w = tid >> 6, lane = tid & 63;
  int q = lane >> 4, ln = lane & 15;
  f32x4 acc[2][8];
#pragma unroll
  for (int mt = 0; mt < 2; ++mt)
#pragma unroll
    for (int nt = 0; nt < 8; ++nt) acc[mt][nt] = (f32x4)0.f;
#pragma unroll
  for (int s = 0; s < 4; ++s) {
    int ko = s * 32 + q * 8;
    bf16x8 a0 = *(bf16x8*)&sA[(w * 32 + ln) * LDP + ko];
    bf16x8 a1 = *(bf16x8*)&sA[(w * 32 + 16 + ln) * LDP + ko];
#pragma unroll
    for (int nt = 0; nt < 8; ++nt) {
      bf16x8 bb = *(bf16x8*)&sB[(nt * 16 + ln) * LDP + ko];
      acc[0][nt] = __builtin_amdgcn_mfma_f32_16x16x32_bf16(a0, bb, acc[0][nt], 0, 0, 0);
      acc[1][nt] = __builtin_amdgcn_mfma_f32_16x16x32_bf16(a1, bb, acc[1][nt], 0, 0, 0);
    }
  }
  float bias8[8];
#pragma unroll
  for (int nt = 0; nt < 8; ++nt) bias8[nt] = biasf[nt * 16 + ln];
#pragma unroll
  for (int mt = 0; mt < 2; ++mt) {
    int rbase = r0 + w * 32 + mt * 16 + q * 4;
#pragma unroll
    for (int r = 0; r < 4; ++r) {
      int gr = rbase + r;
      if (gr < n) {
#pragma unroll
        for (int nt = 0; nt < 8; ++nt) {
          float v = acc[mt][nt][r] + bias8[nt];
          if (relu) v = fmaxf(v, 0.f);
          out[(size_t)gr * 128 + nt * 16 + ln] = __float2bfloat16(v);
        }
      }
    }
  }
}

// fp32 matmul for the head (hg[128,128] @ Wf + bias)
__global__ __launch_bounds__(256) void k_matmul_f32(const float* __restrict__ in,
                                                    const float* __restrict__ W,
                                                    const float* __restrict__ bias,
                                                    float* __restrict__ out, int n,
                                                    int relu) {
  __shared__ float sW[128 * 128];
  __shared__ float sH[64 * 129];
  int tid = threadIdx.x;
  int row0 = blockIdx.x * 64;
  const float4* W4 = (const float4*)W;
  float4* sW4 = (float4*)sW;
#pragma unroll
  for (int i = 0; i < 16; ++i) sW4[tid + i * 256] = W4[tid + i * 256];
  for (int i = tid; i < 64 * 32; i += 256) {
    int r = i >> 5, c4 = i & 31;
    int gr = row0 + r;
    float4 v = make_float4(0.f, 0.f, 0.f, 0.f);
    if (gr < n) v = ((const float4*)(in + (size_t)gr * 128))[c4];
    float* dp = &sH[r * 129 + (c4 << 2)];
    dp[0] = v.x; dp[1] = v.y; dp[2] = v.z; dp[3] = v.w;
  }
  __syncthreads();
  int tx = tid & 15, ty = tid >> 4;
  int col0 = tx * 8;
  float acc[4][8];
#pragma unroll
  for (int i = 0; i < 4; ++i)
#pragma unroll
    for (int j = 0; j < 8; ++j) acc[i][j] = bias[col0 + j];
  for (int k = 0; k < 128; ++k) {
    float hv[4];
#pragma unroll
    for (int i = 0; i < 4; ++i) hv[i] = sH[(ty * 4 + i) * 129 + k];
    const float* wr = &sW[k * 128 + col0];
    float4 wa = *(const float4*)wr;
    float4 wb = *(const float4*)(wr + 4);
    float wv[8] = {wa.x, wa.y, wa.z, wa.w, wb.x, wb.y, wb.z, wb.w};
#pragma unroll
    for (int i = 0; i < 4; ++i)
#pragma unroll
      for (int j = 0; j < 8; ++j) acc[i][j] += hv[i] * wv[j];
  }
#pragma unroll
  for (int i = 0; i < 4; ++i) {
    int gr = row0 + ty * 4 + i;
    if (gr < n) {
      float o[8];
#pragma unroll
      for (int j = 0; j < 8; ++j)
        o[j] = relu ? fmaxf(acc[i][j], 0.f) : acc[i][j];
      float4* dp = (float4*)(out + (size_t)gr * 128 + col0);
      dp[0] = make_float4(o[0], o[1], o[2], o[3]);
      dp[1] = make_float4(o[4], o[5], o[6], o[7]);
    }
  }
}

// CSR propagate on bf16 with packed edge data, unroll-4
__global__ __launch_bounds__(256) void k_prop(const __hip_bfloat16* __restrict__ xw,
                                              const int* __restrict__ row_ptr,
                                              const int2* __restrict__ edat,
                                              const float* __restrict__ dis,
                                              const float* __restrict__ bconv,
                                              __hip_bfloat16* __restrict__ out,
                                              int n) {
  int wave = threadIdx.x >> 6;
  int lane = threadIdx.x & 63;
  int node = blockIdx.x * 4 + wave;
  if (node >= n) return;
  const __hip_bfloat162* x2 = (const __hip_bfloat162*)xw;
  int s = row_ptr[node], e = row_ptr[node + 1];
  float a0 = 0.f, a1 = 0.f;
  int p = s;
  for (; p + 3 < e; p += 4) {
    int2 e0 = edat[p], e1 = edat[p + 1], e2 = edat[p + 2], e3 = edat[p + 3];
    __hip_bfloat162 v0 = x2[(size_t)e0.x * 64 + lane];
    __hip_bfloat162 v1 = x2[(size_t)e1.x * 64 + lane];
    __hip_bfloat162 v2 = x2[(size_t)e2.x * 64 + lane];
    __hip_bfloat162 v3 = x2[(size_t)e3.x * 64 + lane];
    float n0 = __int_as_float(e0.y), n1 = __int_as_float(e1.y);
    float n2 = __int_as_float(e2.y), n3 = __int_as_float(e3.y);
    a0 += n0 * __bfloat162float(v0.x) + n1 * __bfloat162float(v1.x);
    a1 += n0 * __bfloat162float(v0.y) + n1 * __bfloat162float(v1.y);
    a0 += n2 * __bfloat162float(v2.x) + n3 * __bfloat162float(v3.x);
    a1 += n2 * __bfloat162float(v2.y) + n3 * __bfloat162float(v3.y);
  }
  for (; p < e; ++p) {
    int2 e0 = edat[p];
    float n0 = __int_as_float(e0.y);
    __hip_bfloat162 v0 = x2[(size_t)e0.x * 64 + lane];
    a0 += n0 * __bfloat162float(v0.x);
    a1 += n0 * __bfloat162float(v0.y);
  }
  float d = dis[node];
  __hip_bfloat162 vs = x2[(size_t)node * 64 + lane];
  a0 += d * d * __bfloat162float(vs.x);
  a1 += d * d * __bfloat162float(vs.y);
  a0 = fmaxf(a0 + bconv[2 * lane], 0.f);
  a1 = fmaxf(a1 + bconv[2 * lane + 1], 0.f);
  __hip_bfloat162* o2 = (__hip_bfloat162*)out;
  o2[(size_t)node * 64 + lane] =
      __hip_bfloat162{__float2bfloat16(a0), __float2bfloat16(a1)};
}

// node-parallel pool over bf16 h -> fp32 hg (pre-zeroed)
__global__ __launch_bounds__(256) void k_pool(const __hip_bfloat16* __restrict__ h,
                                              const int* __restrict__ batch,
                                              float* __restrict__ hg, int n) {
  int c = threadIdx.x & 127;
  int half = threadIdx.x >> 7;
  int r0 = blockIdx.x * 64;
  int rend = r0 + 64 < n ? r0 + 64 : n;
  float acc = 0.f;
  int cur = -1;
  for (int r = r0 + half; r < rend; r += 2) {
    int g = batch[r];
    if (g != cur) {
      if (cur >= 0) atomicAdd(&hg[cur * 128 + c], acc);
      cur = g;
      acc = 0.f;
    }
    acc += __bfloat162float(h[(size_t)r * 128 + c]);
  }
  if (cur >= 0) atomicAdd(&hg[cur * 128 + c], acc);
}

// final: BN(bn_hid) on hg2, @ w_cls + b_cls, log_softmax. 1 wave / graph.
__global__ __launch_bounds__(64) void k_final(const float* __restrict__ hg2,
                                              const float* __restrict__ sums,
                                              const float* __restrict__ g,
                                              const float* __restrict__ b,
                                              const float* __restrict__ w_cls,
                                              const float* __restrict__ b_cls,
                                              float* __restrict__ out) {
  int gid = blockIdx.x;
  int l = threadIdx.x;
  float m0 = sums[l] * (1.f / 128.f);
  float v0 = sums[128 + l] * (1.f / 128.f) - m0 * m0;
  float A0 = g[l] * rsqrtf(v0 + EPS);
  float B0 = b[l] - A0 * m0;
  float m1 = sums[l + 64] * (1.f / 128.f);
  float v1 = sums[128 + l + 64] * (1.f / 128.f) - m1 * m1;
  float A1 = g[l + 64] * rsqrtf(v1 + EPS);
  float B1 = b[l + 64] - A1 * m1;
  float a0 = A0 * hg2[gid * 128 + l] + B0;
  float a1 = A1 * hg2[gid * 128 + 64 + l] + B1;
  float logit[10];
#pragma unroll
  for (int c = 0; c < 10; ++c) {
    float p = a0 * w_cls[l * 10 + c] + a1 * w_cls[(l + 64) * 10 + c];
#pragma unroll
    for (int off = 32; off; off >>= 1) p += __shfl_xor(p, off, 64);
    logit[c] = p + b_cls[c];
  }
  if (l == 0) {
    float mx = logit[0];
#pragma unroll
    for (int c = 1; c < 10; ++c) mx = fmaxf(mx, logit[c]);
    float se = 0.f;
#pragma unroll
    for (int c = 0; c < 10; ++c) se += expf(logit[c] - mx);
    float lse = mx + logf(se);
#pragma unroll
    for (int c = 0; c < 10; ++c) out[gid * 10 + c] = logit[c] - lse;
  }
}

static inline char* alignp(char* p, size_t a) {
  return (char*)(((uintptr_t)p + a - 1) & ~(a - 1));
}

extern "C" void kernel_launch(void* const* d_in, const int* in_sizes, int n_in,
                              void* d_out, int out_size, void* d_ws, size_t ws_size,
                              hipStream_t stream) {
  const float* x         = (const float*)d_in[0];
  const int*   ei        = (const int*)d_in[1];
  const int*   batch     = (const int*)d_in[2];
  const float* bn_feat_g = (const float*)d_in[3];
  const float* bn_feat_b = (const float*)d_in[4];
  const float* w_feat    = (const float*)d_in[5];
  const float* bn_conv_g = (const float*)d_in[6];
  const float* bn_conv_b = (const float*)d_in[7];
  const float* w_conv    = (const float*)d_in[8];
  const float* b_conv    = (const float*)d_in[9];
  const float* bn_fc_g   = (const float*)d_in[10];
  const float* bn_fc_b   = (const float*)d_in[11];
  const float* w_fc      = (const float*)d_in[12];
  const float* b_fc      = (const float*)d_in[13];
  const float* bn_hid_g  = (const float*)d_in[14];
  const float* bn_hid_b  = (const float*)d_in[15];
  const float* w_cls     = (const float*)d_in[16];
  const float* b_cls     = (const float*)d_in[17];
  float* out = (float*)d_out;

  const int N = in_sizes[0] / 128;
  const int E = in_sizes[1] / 2;
  const int* src = ei;
  const int* dst = ei + E;

  char* p = (char*)d_ws;
  auto carve = [&](size_t bytes) {
    char* q = alignp(p, 256);
    p = q + bytes;
    return q;
  };
  float* dis    = (float*)carve((size_t)N * 4);
  int*   rowp   = (int*)carve((size_t)(N + 1) * 4);
  int*   cursor = (int*)carve((size_t)N * 4);
  int*   bsum   = (int*)carve(256 * 4);
  int2*  edat   = (int2*)carve((size_t)E * 8);
  // single zeroed region: deg | cnt | sums[6][256] | hg
  size_t zbytes = (size_t)2 * N * 4 + 6 * 256 * 4 + 16384 * 4;
  char*  zbase  = carve(zbytes);
  int*   deg    = (int*)zbase;
  int*   cnt    = deg + N;
  float* sums   = (float*)(zbase + (size_t)2 * N * 4);  // 6 buffers of 256
  float* hg     = sums + 6 * 256;
  float* Wf     = (float*)carve(16384 * 4);
  __hip_bfloat16* WfT = (__hip_bfloat16*)carve(16384 * 2);
  float* biasf  = (float*)carve(128 * 4);
  __hip_bfloat16* xb = (__hip_bfloat16*)carve((size_t)N * 128 * 2);
  __hip_bfloat16* h  = (__hip_bfloat16*)carve((size_t)N * 128 * 2);
  __hip_bfloat16* xw = (__hip_bfloat16*)carve((size_t)N * 128 * 2);
  float* hg2    = (float*)carve(16384 * 4);

  const int EB = (E + 255) / 256;
  const int NB = (N + 255) / 256;
  const int MMB = (N + 127) / 128;
  const int PB = (N + 3) / 4;
  const int SB = (N + 1023) / 1024;  // 49 for N=50000 (must be <= 64)

  // --- zero everything that needs it, in one memset ---
  hipMemsetAsync(zbase, 0, zbytes, stream);

  // --- graph preprocessing ---
  k_deg_hist<<<EB, 256, 0, stream>>>(src, dst, E, deg, cnt);
  k_dis<<<NB, 256, 0, stream>>>(deg, dis, N);
  k_scan1<<<SB, 256, 0, stream>>>(cnt, N, rowp, bsum);
  k_scan3<<<SB, 256, 0, stream>>>(rowp, cursor, bsum, N, SB);
  k_scatter<<<EB, 256, 0, stream>>>(src, dst, E, dis, cursor, edat);

  // --- feat layer: h = relu(BN(x) @ w_feat) ---
  k_prep_x<<<256, 256, 0, stream>>>(x, xb, N, sums + 0 * 256);
  k_foldT<<<16, 128, 0, stream>>>(bn_feat_g, bn_feat_b, w_feat, sums + 0 * 256,
                                  1.f / N, WfT, biasf);
  k_matmul_bf16<<<MMB, 256, 0, stream>>>(xb, WfT, biasf, h, N, 1);

  // --- 3 conv layers ---
  for (int i = 0; i < 3; ++i) {
    float* su = sums + (1 + i) * 256;
    k_stats_bf16<<<256, 256, 0, stream>>>(h, N, su);
    k_foldT<<<16, 128, 0, stream>>>(bn_conv_g + i * 128, bn_conv_b + i * 128,
                                    w_conv + (size_t)i * 16384, su, 1.f / N,
                                    WfT, biasf);
    k_matmul_bf16<<<MMB, 256, 0, stream>>>(h, WfT, biasf, xw, N, 0);
    k_prop<<<PB, 256, 0, stream>>>(xw, rowp, edat, dis, b_conv + i * 128, h, N);
  }

  // --- pool + head (fp32) ---
  k_pool<<<(N + 63) / 64, 256, 0, stream>>>(h, batch, hg, N);

  k_stats<<<16, 256, 0, stream>>>(hg, 128, sums + 4 * 256);
  k_fold<<<16, 128, 0, stream>>>(bn_fc_g, bn_fc_b, w_fc, sums + 4 * 256,
                                 1.f / 128.f, b_fc, Wf, biasf);
  k_matmul_f32<<<2, 256, 0, stream>>>(hg, Wf, biasf, hg2, 128, 1);

  k_stats<<<16, 256, 0, stream>>>(hg2, 128, sums + 5 * 256);
  k_final<<<128, 64, 0, stream>>>(hg2, sums + 5 * 256, bn_hid_g, bn_hid_b,
                                  w_cls, b_cls, out);
}